// Round 1
// baseline (1782.275 us; speedup 1.0000x reference)
//
#include <hip/hip_runtime.h>
#include <hip/hip_bf16.h>
#include <float.h>

// Problem constants (from reference)
#define NN 20000
#define EE 320000
#define IN_DIM 128
#define HIDD 64
#define CLSD 32
#define H0_ 4
#define H1_ 4
#define H2_ 6
#define SLOPE_ 0.2f

// ---------- helpers ----------
__device__ inline unsigned int enc_f(float f) {
    unsigned int u = __float_as_uint(f);
    return (u & 0x80000000u) ? ~u : (u | 0x80000000u);
}
__device__ inline float dec_f(unsigned int u) {
    return __uint_as_float((u & 0x80000000u) ? (u ^ 0x80000000u) : ~u);
}

// ---------- GEMM: C[M,Nc] = A[M,K] @ W[K,Nc] + bias ----------
// 64x64 block tile, BK=16, 256 threads (16x16), 4x4 microtile per thread.
__global__ void gemm_bias(const float* __restrict__ A, const float* __restrict__ W,
                          const float* __restrict__ bias, float* __restrict__ C,
                          int M, int K, int Nc) {
    __shared__ float As[16][65];  // [k][m]
    __shared__ float Bs[16][65];  // [k][n]
    const int tx = threadIdx.x;       // 0..15
    const int ty = threadIdx.y;       // 0..15
    const int tid = ty * 16 + tx;
    const int block_m = blockIdx.y * 64;
    const int block_n = blockIdx.x * 64;

    float acc[4][4] = {};

    for (int k0 = 0; k0 < K; k0 += 16) {
        // load A tile (64 rows x 16 k), store transposed
        #pragma unroll
        for (int i = tid; i < 64 * 16; i += 256) {
            int m = i >> 4, kk = i & 15;
            int row = block_m + m;
            As[kk][m] = (row < M) ? A[(size_t)row * K + k0 + kk] : 0.f;
        }
        // load W tile (16 k x 64 n)
        #pragma unroll
        for (int i = tid; i < 16 * 64; i += 256) {
            int kk = i >> 6, n = i & 63;
            Bs[kk][n] = W[(size_t)(k0 + kk) * Nc + block_n + n];
        }
        __syncthreads();
        #pragma unroll
        for (int kk = 0; kk < 16; ++kk) {
            float a[4], b[4];
            #pragma unroll
            for (int i = 0; i < 4; ++i) a[i] = As[kk][ty * 4 + i];
            #pragma unroll
            for (int j = 0; j < 4; ++j) b[j] = Bs[kk][tx * 4 + j];
            #pragma unroll
            for (int i = 0; i < 4; ++i)
                #pragma unroll
                for (int j = 0; j < 4; ++j) acc[i][j] += a[i] * b[j];
        }
        __syncthreads();
    }
    #pragma unroll
    for (int i = 0; i < 4; ++i) {
        int row = block_m + ty * 4 + i;
        if (row >= M) continue;
        #pragma unroll
        for (int j = 0; j < 4; ++j) {
            int col = block_n + tx * 4 + j;
            C[(size_t)row * Nc + col] = acc[i][j] + bias[col];
        }
    }
}

// ---------- init m_enc (= enc(-inf)) and denom (= 0) ----------
__global__ void init_md(unsigned int* __restrict__ m_enc, float* __restrict__ denom, int n) {
    int i = blockIdx.x * blockDim.x + threadIdx.x;
    if (i < n) {
        m_enc[i] = 0x007FFFFFu;  // enc(-inf)
        denom[i] = 0.f;
    }
}

__global__ void zero_f(float* __restrict__ p, int n) {
    int i = blockIdx.x * blockDim.x + threadIdx.x;
    if (i < n) p[i] = 0.f;
}

__global__ void copy_f(const float* __restrict__ a, float* __restrict__ b, int n) {
    int i = blockIdx.x * blockDim.x + threadIdx.x;
    if (i < n) b[i] = a[i];
}

// ---------- edge logits + segment max ----------
// one 64-lane wave per edge; 256 threads/block = 4 edges/block
__global__ void edge_logits_kernel(const float* __restrict__ fs, const float* __restrict__ fd,
                                   const float* __restrict__ attn,
                                   const int* __restrict__ src, const int* __restrict__ dst,
                                   float* __restrict__ logits, unsigned int* __restrict__ m_enc,
                                   int E, int H, int D, int HD) {
    int e = blockIdx.x * 4 + (threadIdx.x >> 6);
    int lane = threadIdx.x & 63;
    if (e >= E) return;
    int s = src[e], t = dst[e];
    const float* pfs = fs + (size_t)s * HD;
    const float* pfd = fd + (size_t)t * HD;
    for (int k = 0; k * 64 < HD; ++k) {
        int idx = k * 64 + lane;
        float v = pfs[idx] + pfd[idx];
        v = v > 0.f ? v : SLOPE_ * v;
        float p = v * attn[idx];
        // reduce within D-lane groups (D is 64 or 32, power of two)
        for (int off = 1; off < D; off <<= 1)
            p += __shfl_xor(p, off, 64);
        if ((lane & (D - 1)) == 0) {
            int hh = idx / D;
            logits[(size_t)e * H + hh] = p;
            atomicMax(&m_enc[(size_t)t * H + hh], enc_f(p));
        }
    }
}

// ---------- exp(logit - m[dst]) and denom accumulation ----------
__global__ void edge_expsum(const int* __restrict__ dst, const unsigned int* __restrict__ m_enc,
                            float* __restrict__ logits, float* __restrict__ denom,
                            int E, int H) {
    int tid = blockIdx.x * blockDim.x + threadIdx.x;
    if (tid >= E * H) return;
    int e = tid / H;
    int hh = tid - e * H;
    int t = dst[e];
    float m = dec_f(m_enc[(size_t)t * H + hh]);
    float ex = __expf(logits[tid] - m);
    logits[tid] = ex;
    atomicAdd(&denom[(size_t)t * H + hh], ex);
}

// ---------- alpha-weighted scatter-add ----------
__global__ void edge_aggregate(const float* __restrict__ fs,
                               const int* __restrict__ src, const int* __restrict__ dst,
                               const float* __restrict__ ex, const float* __restrict__ denom,
                               float* __restrict__ out, int E, int H, int D, int HD) {
    int e = blockIdx.x * 4 + (threadIdx.x >> 6);
    int lane = threadIdx.x & 63;
    if (e >= E) return;
    int s = src[e], t = dst[e];
    const float* pfs = fs + (size_t)s * HD;
    float* pout = out + (size_t)t * HD;
    for (int k = 0; k * 64 < HD; ++k) {
        int idx = k * 64 + lane;
        int hh = idx / D;
        float alpha = ex[(size_t)e * H + hh] / denom[(size_t)t * H + hh];
        atomicAdd(&pout[idx], alpha * pfs[idx]);
    }
}

// ---------- ELU ----------
__global__ void elu_kernel(float* __restrict__ p, int n) {
    int i = blockIdx.x * blockDim.x + threadIdx.x;
    if (i < n) {
        float v = p[i];
        p[i] = v > 0.f ? v : expm1f(v);
    }
}

// ---------- mean over heads: [N, 6, 32] -> [N, 32] ----------
__global__ void mean_heads(const float* __restrict__ out3, float* __restrict__ y, int n) {
    int i = blockIdx.x * blockDim.x + threadIdx.x;
    if (i >= n) return;
    int node = i >> 5;        // /32
    int c = i & 31;
    const float* p = out3 + (size_t)node * (H2_ * CLSD) + c;
    float sum = 0.f;
    #pragma unroll
    for (int h = 0; h < H2_; ++h) sum += p[h * CLSD];
    y[i] = sum * (1.f / 6.f);
}

// ---------- layer driver (host side) ----------
static void run_layer(const float* h, int F,
                      const float* Ws, const float* bs,
                      const float* Wd, const float* bd,
                      const float* attn,
                      const int* src, const int* dst,
                      int H, int D,
                      float* fs, float* fd, float* out,
                      float* exbuf, float* denom, unsigned int* m_enc,
                      int res_mode, const float* Wr, const float* br,
                      bool do_elu, hipStream_t stream) {
    const int HD = H * D;
    dim3 gblock(16, 16);
    dim3 ggrid((HD + 63) / 64, (NN + 63) / 64);
    gemm_bias<<<ggrid, gblock, 0, stream>>>(h, Ws, bs, fs, NN, F, HD);
    gemm_bias<<<ggrid, gblock, 0, stream>>>(h, Wd, bd, fd, NN, F, HD);

    int nmd = NN * H;
    init_md<<<(nmd + 255) / 256, 256, 0, stream>>>(m_enc, denom, nmd);

    int nout = NN * HD;
    if (res_mode == 0) {
        zero_f<<<(nout + 255) / 256, 256, 0, stream>>>(out, nout);
    } else if (res_mode == 1) {
        copy_f<<<(nout + 255) / 256, 256, 0, stream>>>(h, out, nout);
    } else {
        gemm_bias<<<ggrid, gblock, 0, stream>>>(h, Wr, br, out, NN, F, HD);
    }

    int eblocks = (EE + 3) / 4;
    edge_logits_kernel<<<eblocks, 256, 0, stream>>>(fs, fd, attn, src, dst, exbuf, m_enc,
                                                    EE, H, D, HD);
    int neh = EE * H;
    edge_expsum<<<(neh + 255) / 256, 256, 0, stream>>>(dst, m_enc, exbuf, denom, EE, H);
    edge_aggregate<<<eblocks, 256, 0, stream>>>(fs, src, dst, exbuf, denom, out, EE, H, D, HD);

    if (do_elu) {
        elu_kernel<<<(nout + 255) / 256, 256, 0, stream>>>(out, nout);
    }
}

extern "C" void kernel_launch(void* const* d_in, const int* in_sizes, int n_in,
                              void* d_out, int out_size, void* d_ws, size_t ws_size,
                              hipStream_t stream) {
    const float* x   = (const float*)d_in[0];
    const int*   src = (const int*)d_in[1];
    const int*   dst = (const int*)d_in[2];
    const float* W0s = (const float*)d_in[3];
    const float* b0s = (const float*)d_in[4];
    const float* W0d = (const float*)d_in[5];
    const float* b0d = (const float*)d_in[6];
    const float* a0  = (const float*)d_in[7];
    const float* W1s = (const float*)d_in[8];
    const float* b1s = (const float*)d_in[9];
    const float* W1d = (const float*)d_in[10];
    const float* b1d = (const float*)d_in[11];
    const float* a1  = (const float*)d_in[12];
    const float* W2s = (const float*)d_in[13];
    const float* b2s = (const float*)d_in[14];
    const float* W2d = (const float*)d_in[15];
    const float* b2d = (const float*)d_in[16];
    const float* a2  = (const float*)d_in[17];
    const float* Wr2 = (const float*)d_in[18];
    const float* br2 = (const float*)d_in[19];

    // workspace layout (floats)
    float* fs    = (float*)d_ws;            // N*256
    float* fd    = fs + (size_t)NN * 256;   // N*256
    float* O0    = fd + (size_t)NN * 256;   // N*256  (layer0 out; reused for layer2 out)
    float* O1    = O0 + (size_t)NN * 256;   // N*256  (layer1 out)
    float* exbuf = O1 + (size_t)NN * 256;   // E*6
    float* denom = exbuf + (size_t)EE * 6;  // N*6
    unsigned int* m_enc = (unsigned int*)(denom + (size_t)NN * 6);  // N*6

    // layer 0: in x[N,128] -> O0[N,256], no residual, ELU
    run_layer(x, IN_DIM, W0s, b0s, W0d, b0d, a0, src, dst, H0_, HIDD,
              fs, fd, O0, exbuf, denom, m_enc, 0, nullptr, nullptr, true, stream);
    // layer 1: in O0[N,256] -> O1[N,256], identity residual, ELU
    run_layer(O0, H0_ * HIDD, W1s, b1s, W1d, b1d, a1, src, dst, H1_, HIDD,
              fs, fd, O1, exbuf, denom, m_enc, 1, nullptr, nullptr, true, stream);
    // layer 2: in O1[N,256] -> O0[N,192], projected residual, no activation
    run_layer(O1, H1_ * HIDD, W2s, b2s, W2d, b2d, a2, src, dst, H2_, CLSD,
              fs, fd, O0, exbuf, denom, m_enc, 2, Wr2, br2, false, stream);

    // final: mean over heads -> d_out [N,32]
    float* y = (float*)d_out;
    int nout = NN * CLSD;
    mean_heads<<<(nout + 255) / 256, 256, 0, stream>>>(O0, y, nout);
}

// Round 2
// 816.487 us; speedup vs baseline: 2.1829x; 2.1829x over previous
//
#include <hip/hip_runtime.h>
#include <hip/hip_bf16.h>
#include <float.h>
#include <math.h>

// Problem constants (from reference)
#define NN 20000
#define EE 320000
#define IN_DIM 128
#define HIDD 64
#define CLSD 32
#define H0_ 4
#define H1_ 4
#define H2_ 6
#define SLOPE_ 0.2f

// ---------- GEMM: C[M,Nc] = A[M,K] @ W[K,Nc] + bias ----------
// 64x64 block tile, BK=16, 256 threads (16x16), 4x4 microtile per thread.
__global__ void gemm_bias(const float* __restrict__ A, const float* __restrict__ W,
                          const float* __restrict__ bias, float* __restrict__ C,
                          int M, int K, int Nc) {
    __shared__ float As[16][65];  // [k][m]
    __shared__ float Bs[16][65];  // [k][n]
    const int tx = threadIdx.x;       // 0..15
    const int ty = threadIdx.y;       // 0..15
    const int tid = ty * 16 + tx;
    const int block_m = blockIdx.y * 64;
    const int block_n = blockIdx.x * 64;

    float acc[4][4] = {};

    for (int k0 = 0; k0 < K; k0 += 16) {
        #pragma unroll
        for (int i = tid; i < 64 * 16; i += 256) {
            int m = i >> 4, kk = i & 15;
            int row = block_m + m;
            As[kk][m] = (row < M) ? A[(size_t)row * K + k0 + kk] : 0.f;
        }
        #pragma unroll
        for (int i = tid; i < 16 * 64; i += 256) {
            int kk = i >> 6, n = i & 63;
            Bs[kk][n] = W[(size_t)(k0 + kk) * Nc + block_n + n];
        }
        __syncthreads();
        #pragma unroll
        for (int kk = 0; kk < 16; ++kk) {
            float a[4], b[4];
            #pragma unroll
            for (int i = 0; i < 4; ++i) a[i] = As[kk][ty * 4 + i];
            #pragma unroll
            for (int j = 0; j < 4; ++j) b[j] = Bs[kk][tx * 4 + j];
            #pragma unroll
            for (int i = 0; i < 4; ++i)
                #pragma unroll
                for (int j = 0; j < 4; ++j) acc[i][j] += a[i] * b[j];
        }
        __syncthreads();
    }
    #pragma unroll
    for (int i = 0; i < 4; ++i) {
        int row = block_m + ty * 4 + i;
        if (row >= M) continue;
        #pragma unroll
        for (int j = 0; j < 4; ++j) {
            int col = block_n + tx * 4 + j;
            C[(size_t)row * Nc + col] = acc[i][j] + bias[col];
        }
    }
}

// ---------- CSR build ----------
__global__ void zero_u32(unsigned int* __restrict__ p, int n) {
    int i = blockIdx.x * blockDim.x + threadIdx.x;
    if (i < n) p[i] = 0u;
}

__global__ void hist_dst(const int* __restrict__ dst, unsigned int* __restrict__ deg, int E) {
    int e = blockIdx.x * blockDim.x + threadIdx.x;
    if (e < E) atomicAdd(&deg[dst[e]], 1u);
}

// single-block exclusive scan of deg[0..n) -> row_ptr[0..n], also copies to cursor
__global__ void scan_deg(const unsigned int* __restrict__ deg,
                         unsigned int* __restrict__ row_ptr,
                         unsigned int* __restrict__ cursor, int n) {
    __shared__ unsigned int sums[1024];
    const int t = threadIdx.x;
    const int chunk = (n + 1023) / 1024;
    const int start = t * chunk;
    const int end = min(start + chunk, n);
    unsigned int s = 0;
    for (int i = start; i < end; ++i) s += deg[i];
    sums[t] = s;
    __syncthreads();
    // Hillis-Steele inclusive scan over 1024 partial sums
    for (int off = 1; off < 1024; off <<= 1) {
        unsigned int v = (t >= off) ? sums[t - off] : 0u;
        __syncthreads();
        sums[t] += v;
        __syncthreads();
    }
    unsigned int prefix = (t == 0) ? 0u : sums[t - 1];
    for (int i = start; i < end; ++i) {
        row_ptr[i] = prefix;
        cursor[i] = prefix;
        prefix += deg[i];
    }
    if (t == 1023) row_ptr[n] = sums[1023];
}

__global__ void scatter_edges(const int* __restrict__ src, const int* __restrict__ dst,
                              unsigned int* __restrict__ cursor,
                              int* __restrict__ csr_src, int E) {
    int e = blockIdx.x * blockDim.x + threadIdx.x;
    if (e < E) {
        unsigned int pos = atomicAdd(&cursor[dst[e]], 1u);
        csr_src[pos] = src[e];
    }
}

// ---------- fused GATv2: logits + online softmax + aggregate + residual (+ELU / +head-mean) ----------
// One 64-lane wave per destination node; 4 nodes per 256-thread block.
// KMAX = HD/64 registers per lane; D = head dim (64 or 32).
template <int KMAX, int D, bool HAS_RES, bool DO_ELU, bool MEAN_OUT>
__global__ void gat_fused_aggregate(const float* __restrict__ fs, const float* __restrict__ fd,
                                    const float* __restrict__ attn,
                                    const unsigned int* __restrict__ row_ptr,
                                    const int* __restrict__ csr_src,
                                    const float* __restrict__ resid,
                                    float* __restrict__ out) {
    const int t = blockIdx.x * 4 + (threadIdx.x >> 6);
    const int lane = threadIdx.x & 63;
    if (t >= NN) return;
    const int HD = KMAX * 64;

    float fdv[KMAX], attnv[KMAX], acc[KMAX], mh[KMAX], lh[KMAX];
    #pragma unroll
    for (int k = 0; k < KMAX; ++k) {
        int idx = k * 64 + lane;
        fdv[k] = fd[(size_t)t * HD + idx];
        attnv[k] = attn[idx];
        acc[k] = 0.f;
        lh[k] = 0.f;
        mh[k] = -INFINITY;
    }

    const unsigned int j0 = row_ptr[t], j1 = row_ptr[t + 1];
    for (unsigned int j = j0; j < j1; ++j) {
        const int s = csr_src[j];
        const float* __restrict__ pfs = fs + (size_t)s * HD;
        #pragma unroll
        for (int k = 0; k < KMAX; ++k) {
            int idx = k * 64 + lane;
            float fsv = pfs[idx];
            float v = fsv + fdv[k];
            v = v > 0.f ? v : SLOPE_ * v;
            float p = v * attnv[k];
            // butterfly reduce within each D-lane group -> every lane holds its head's logit
            #pragma unroll
            for (int off = 1; off < D; off <<= 1)
                p += __shfl_xor(p, off, 64);
            // online softmax update
            float nm = fmaxf(mh[k], p);
            float sc = __expf(mh[k] - nm);   // exp(-inf)=0 on first edge
            float w = __expf(p - nm);
            lh[k] = lh[k] * sc + w;
            acc[k] = acc[k] * sc + w * fsv;
            mh[k] = nm;
        }
    }

    float vout[KMAX];
    #pragma unroll
    for (int k = 0; k < KMAX; ++k) {
        float val = (lh[k] > 0.f) ? acc[k] / lh[k] : 0.f;
        if (HAS_RES) {
            int idx = k * 64 + lane;
            val += resid[(size_t)t * HD + idx];
        }
        if (DO_ELU) val = val > 0.f ? val : expm1f(val);
        vout[k] = val;
    }

    if (MEAN_OUT) {
        // layer 2: [6 heads x 32 cols]; lane<32 holds heads {0,2,4} at col=lane,
        // lane>=32 holds heads {1,3,5} at col=lane-32. Sum k, then xor-32 across halves.
        float ssum = 0.f;
        #pragma unroll
        for (int k = 0; k < KMAX; ++k) ssum += vout[k];
        ssum += __shfl_xor(ssum, 32, 64);
        if (lane < 32) out[(size_t)t * 32 + lane] = ssum * (1.f / 6.f);
    } else {
        #pragma unroll
        for (int k = 0; k < KMAX; ++k)
            out[(size_t)t * HD + k * 64 + lane] = vout[k];
    }
}

extern "C" void kernel_launch(void* const* d_in, const int* in_sizes, int n_in,
                              void* d_out, int out_size, void* d_ws, size_t ws_size,
                              hipStream_t stream) {
    const float* x   = (const float*)d_in[0];
    const int*   src = (const int*)d_in[1];
    const int*   dst = (const int*)d_in[2];
    const float* W0s = (const float*)d_in[3];
    const float* b0s = (const float*)d_in[4];
    const float* W0d = (const float*)d_in[5];
    const float* b0d = (const float*)d_in[6];
    const float* a0  = (const float*)d_in[7];
    const float* W1s = (const float*)d_in[8];
    const float* b1s = (const float*)d_in[9];
    const float* W1d = (const float*)d_in[10];
    const float* b1d = (const float*)d_in[11];
    const float* a1  = (const float*)d_in[12];
    const float* W2s = (const float*)d_in[13];
    const float* b2s = (const float*)d_in[14];
    const float* W2d = (const float*)d_in[15];
    const float* b2d = (const float*)d_in[16];
    const float* a2  = (const float*)d_in[17];
    const float* Wr2 = (const float*)d_in[18];
    const float* br2 = (const float*)d_in[19];

    // workspace layout
    float* fs = (float*)d_ws;                       // N*256
    float* fd = fs + (size_t)NN * 256;              // N*256
    float* O0 = fd + (size_t)NN * 256;              // N*256 (layer0 out; reused as layer2 residual)
    float* O1 = O0 + (size_t)NN * 256;              // N*256 (layer1 out)
    unsigned int* row_ptr = (unsigned int*)(O1 + (size_t)NN * 256);  // N+1
    unsigned int* cursor  = row_ptr + (NN + 1);     // N
    unsigned int* deg     = cursor + NN;            // N
    int* csr_src          = (int*)(deg + NN);       // E

    // ---- build CSR (once per call, reused by all 3 layers) ----
    zero_u32<<<(NN + 255) / 256, 256, 0, stream>>>(deg, NN);
    hist_dst<<<(EE + 255) / 256, 256, 0, stream>>>(dst, deg, EE);
    scan_deg<<<1, 1024, 0, stream>>>(deg, row_ptr, cursor, NN);
    scatter_edges<<<(EE + 255) / 256, 256, 0, stream>>>(src, dst, cursor, csr_src, EE);

    dim3 gblock(16, 16);
    const int nblocks = (NN + 3) / 4;

    // ---- layer 0: x[N,128] -> O0[N,256], no residual, ELU ----
    {
        dim3 ggrid(256 / 64, (NN + 63) / 64);
        gemm_bias<<<ggrid, gblock, 0, stream>>>(x, W0s, b0s, fs, NN, IN_DIM, 256);
        gemm_bias<<<ggrid, gblock, 0, stream>>>(x, W0d, b0d, fd, NN, IN_DIM, 256);
        gat_fused_aggregate<4, 64, false, true, false><<<nblocks, 256, 0, stream>>>(
            fs, fd, a0, row_ptr, csr_src, nullptr, O0);
    }
    // ---- layer 1: O0[N,256] -> O1[N,256], identity residual, ELU ----
    {
        dim3 ggrid(256 / 64, (NN + 63) / 64);
        gemm_bias<<<ggrid, gblock, 0, stream>>>(O0, W1s, b1s, fs, NN, 256, 256);
        gemm_bias<<<ggrid, gblock, 0, stream>>>(O0, W1d, b1d, fd, NN, 256, 256);
        gat_fused_aggregate<4, 64, true, true, false><<<nblocks, 256, 0, stream>>>(
            fs, fd, a1, row_ptr, csr_src, O0, O1);
    }
    // ---- layer 2: O1[N,256] -> y[N,32], projected residual, no act, head-mean ----
    {
        dim3 ggrid(192 / 64, (NN + 63) / 64);
        gemm_bias<<<ggrid, gblock, 0, stream>>>(O1, W2s, b2s, fs, NN, 256, 192);
        gemm_bias<<<ggrid, gblock, 0, stream>>>(O1, W2d, b2d, fd, NN, 256, 192);
        gemm_bias<<<ggrid, gblock, 0, stream>>>(O1, Wr2, br2, O0, NN, 256, 192);  // residual proj
        gat_fused_aggregate<3, 32, true, false, true><<<nblocks, 256, 0, stream>>>(
            fs, fd, a2, row_ptr, csr_src, O0, (float*)d_out);
    }
}

// Round 3
// 567.029 us; speedup vs baseline: 3.1432x; 1.4399x over previous
//
#include <hip/hip_runtime.h>
#include <hip/hip_bf16.h>
#include <float.h>
#include <math.h>

// Problem constants (from reference)
#define NN 20000
#define EE 320000
#define IN_DIM 128
#define SLOPE_ 0.2f

typedef __attribute__((ext_vector_type(8))) short bf16x8;
typedef __attribute__((ext_vector_type(4))) float f32x4;
typedef unsigned short ushort;

// ---------- bf16 helpers ----------
__device__ inline ushort f32_to_bf16_rn(float f) {
    unsigned u = __float_as_uint(f);
    unsigned rounding = 0x7FFFu + ((u >> 16) & 1u);
    return (ushort)((u + rounding) >> 16);
}
__device__ inline float bf16u_to_f32(ushort h) {
    return __uint_as_float(((unsigned)h) << 16);
}

// ---------- split fp32 -> (hi, lo) bf16 ----------
__global__ void split_f32(const float* __restrict__ A, ushort* __restrict__ hi,
                          ushort* __restrict__ lo, int n4) {
    int i = blockIdx.x * blockDim.x + threadIdx.x;
    if (i >= n4) return;
    float4 v = ((const float4*)A)[i];
    ushort h0 = f32_to_bf16_rn(v.x), h1 = f32_to_bf16_rn(v.y);
    ushort h2 = f32_to_bf16_rn(v.z), h3 = f32_to_bf16_rn(v.w);
    ushort l0 = f32_to_bf16_rn(v.x - bf16u_to_f32(h0));
    ushort l1 = f32_to_bf16_rn(v.y - bf16u_to_f32(h1));
    ushort l2 = f32_to_bf16_rn(v.z - bf16u_to_f32(h2));
    ushort l3 = f32_to_bf16_rn(v.w - bf16u_to_f32(h3));
    ((ushort4*)hi)[i] = make_ushort4(h0, h1, h2, h3);
    ((ushort4*)lo)[i] = make_ushort4(l0, l1, l2, l3);
}

// ---------- weight prep: concat + transpose + split, plus bias concat ----------
// Wa [K x na], Wb [K x nb], Wc [K x nc] -> Wt_hi/lo [(na+nb+nc) x K]
__global__ void prep_w(const float* __restrict__ Wa, const float* __restrict__ ba, int na,
                       const float* __restrict__ Wb, const float* __restrict__ bb, int nb,
                       const float* __restrict__ Wc, const float* __restrict__ bc, int nc,
                       int K, ushort* __restrict__ Wt_hi, ushort* __restrict__ Wt_lo,
                       float* __restrict__ bias_cat) {
    int idx = blockIdx.x * blockDim.x + threadIdx.x;
    int S = na + nb + nc;
    if (idx >= S * K) return;
    int n = idx / K;
    int k = idx - n * K;
    const float* W; const float* b; int nl; int ncols;
    if (n < na) { W = Wa; b = ba; nl = n; ncols = na; }
    else if (n < na + nb) { W = Wb; b = bb; nl = n - na; ncols = nb; }
    else { W = Wc; b = bc; nl = n - na - nb; ncols = nc; }
    float v = W[(size_t)k * ncols + nl];
    ushort h = f32_to_bf16_rn(v);
    ushort l = f32_to_bf16_rn(v - bf16u_to_f32(h));
    Wt_hi[(size_t)n * K + k] = h;
    Wt_lo[(size_t)n * K + k] = l;
    if (k == 0) bias_cat[n] = b[nl];
}

// ---------- split-bf16 MFMA GEMM: C[M][S] = A[M][K] @ Wt^T + bias ----------
// BM=128, BN=64, BK=32. 256 threads = 4 waves; wave owns 32 rows (2 m-tiles of 16).
// A fragments loaded direct global->VGPR (no cross-wave A reuse). B staged in LDS.
#define BSTRIDE 40  // 32 + 8 pad (<=2-way bank conflicts, free)
__global__ __launch_bounds__(256) void gemm_mfma_split(
        const ushort* __restrict__ Ahi, const ushort* __restrict__ Alo,
        const ushort* __restrict__ Wth, const ushort* __restrict__ Wtl,
        const float* __restrict__ bias, float* __restrict__ C,
        int M, int K, int S) {
    __shared__ ushort Bs_hi[64 * BSTRIDE];
    __shared__ ushort Bs_lo[64 * BSTRIDE];
    const int bm = blockIdx.y * 128;
    const int bn = blockIdx.x * 64;
    const int tid = threadIdx.x;
    const int wave = tid >> 6;
    const int lane = tid & 63;
    const int m16 = lane & 15;
    const int quad = lane >> 4;

    f32x4 acc[2][4];
    #pragma unroll
    for (int i = 0; i < 2; ++i)
        #pragma unroll
        for (int j = 0; j < 4; ++j) acc[i][j] = (f32x4){0.f, 0.f, 0.f, 0.f};

    const int srow = tid >> 2;   // 0..63: B staging row
    const int schk = tid & 3;    // 16B chunk within 32-elem row

    for (int k0 = 0; k0 < K; k0 += 32) {
        // --- stage B tile (64 x 32 hi+lo) ---
        {
            size_t goff = (size_t)(bn + srow) * K + k0 + schk * 8;
            bf16x8 vh = *(const bf16x8*)(Wth + goff);
            bf16x8 vl = *(const bf16x8*)(Wtl + goff);
            *(bf16x8*)&Bs_hi[srow * BSTRIDE + schk * 8] = vh;
            *(bf16x8*)&Bs_lo[srow * BSTRIDE + schk * 8] = vl;
        }
        // --- A fragments direct from global ---
        bf16x8 ah[2], al[2];
        #pragma unroll
        for (int mt = 0; mt < 2; ++mt) {
            int row = bm + wave * 32 + mt * 16 + m16;
            row = row < M ? row : M - 1;
            size_t goff = (size_t)row * K + k0 + quad * 8;
            ah[mt] = *(const bf16x8*)(Ahi + goff);
            al[mt] = *(const bf16x8*)(Alo + goff);
        }
        __syncthreads();
        #pragma unroll
        for (int nt = 0; nt < 4; ++nt) {
            int boff = (nt * 16 + m16) * BSTRIDE + quad * 8;
            bf16x8 bh = *(const bf16x8*)&Bs_hi[boff];
            bf16x8 bl = *(const bf16x8*)&Bs_lo[boff];
            #pragma unroll
            for (int mt = 0; mt < 2; ++mt) {
                acc[mt][nt] = __builtin_amdgcn_mfma_f32_16x16x32_bf16(ah[mt], bh, acc[mt][nt], 0, 0, 0);
                acc[mt][nt] = __builtin_amdgcn_mfma_f32_16x16x32_bf16(ah[mt], bl, acc[mt][nt], 0, 0, 0);
                acc[mt][nt] = __builtin_amdgcn_mfma_f32_16x16x32_bf16(al[mt], bh, acc[mt][nt], 0, 0, 0);
            }
        }
        __syncthreads();
    }

    // epilogue: C/D layout col=lane&15, row=quad*4+reg
    #pragma unroll
    for (int nt = 0; nt < 4; ++nt) {
        int col = bn + nt * 16 + m16;
        float bv = bias[col];
        #pragma unroll
        for (int mt = 0; mt < 2; ++mt) {
            #pragma unroll
            for (int r = 0; r < 4; ++r) {
                int row = bm + wave * 32 + mt * 16 + quad * 4 + r;
                if (row < M) C[(size_t)row * S + col] = acc[mt][nt][r] + bv;
            }
        }
    }
}

// ---------- CSR build ----------
__global__ void zero_u32(unsigned int* __restrict__ p, int n) {
    int i = blockIdx.x * blockDim.x + threadIdx.x;
    if (i < n) p[i] = 0u;
}

__global__ void hist_dst(const int* __restrict__ dst, unsigned int* __restrict__ deg, int E) {
    int e = blockIdx.x * blockDim.x + threadIdx.x;
    if (e < E) atomicAdd(&deg[dst[e]], 1u);
}

__global__ void scan_deg(const unsigned int* __restrict__ deg,
                         unsigned int* __restrict__ row_ptr,
                         unsigned int* __restrict__ cursor, int n) {
    __shared__ unsigned int sums[1024];
    const int t = threadIdx.x;
    const int chunk = (n + 1023) / 1024;
    const int start = t * chunk;
    const int end = min(start + chunk, n);
    unsigned int s = 0;
    for (int i = start; i < end; ++i) s += deg[i];
    sums[t] = s;
    __syncthreads();
    for (int off = 1; off < 1024; off <<= 1) {
        unsigned int v = (t >= off) ? sums[t - off] : 0u;
        __syncthreads();
        sums[t] += v;
        __syncthreads();
    }
    unsigned int prefix = (t == 0) ? 0u : sums[t - 1];
    for (int i = start; i < end; ++i) {
        row_ptr[i] = prefix;
        cursor[i] = prefix;
        prefix += deg[i];
    }
    if (t == 1023) row_ptr[n] = sums[1023];
}

__global__ void scatter_edges(const int* __restrict__ src, const int* __restrict__ dst,
                              unsigned int* __restrict__ cursor,
                              int* __restrict__ csr_src, int E) {
    int e = blockIdx.x * blockDim.x + threadIdx.x;
    if (e < E) {
        unsigned int pos = atomicAdd(&cursor[dst[e]], 1u);
        csr_src[pos] = src[e];
    }
}

// ---------- fused GATv2 aggregate (CSR gather + online softmax) ----------
// feat rows: [fs(HD) | fd(HD) | (res HD)], row stride FS.
template <int KMAX, int D, bool HAS_RES, bool DO_ELU, bool MEAN_OUT>
__global__ void gat_fused_aggregate(const float* __restrict__ feat, int FS,
                                    const float* __restrict__ attn,
                                    const unsigned int* __restrict__ row_ptr,
                                    const int* __restrict__ csr_src,
                                    const float* __restrict__ resid, int RS,
                                    float* __restrict__ out) {
    const int t = blockIdx.x * 4 + (threadIdx.x >> 6);
    const int lane = threadIdx.x & 63;
    if (t >= NN) return;
    const int HD = KMAX * 64;

    float fdv[KMAX], attnv[KMAX], acc[KMAX], mh[KMAX], lh[KMAX];
    #pragma unroll
    for (int k = 0; k < KMAX; ++k) {
        int idx = k * 64 + lane;
        fdv[k] = feat[(size_t)t * FS + HD + idx];
        attnv[k] = attn[idx];
        acc[k] = 0.f;
        lh[k] = 0.f;
        mh[k] = -INFINITY;
    }

    const unsigned int j0 = row_ptr[t], j1 = row_ptr[t + 1];
    for (unsigned int j = j0; j < j1; ++j) {
        const int s = csr_src[j];
        const float* __restrict__ pfs = feat + (size_t)s * FS;
        #pragma unroll
        for (int k = 0; k < KMAX; ++k) {
            int idx = k * 64 + lane;
            float fsv = pfs[idx];
            float v = fsv + fdv[k];
            v = v > 0.f ? v : SLOPE_ * v;
            float p = v * attnv[k];
            #pragma unroll
            for (int off = 1; off < D; off <<= 1)
                p += __shfl_xor(p, off, 64);
            float nm = fmaxf(mh[k], p);
            float sc = __expf(mh[k] - nm);
            float w = __expf(p - nm);
            lh[k] = lh[k] * sc + w;
            acc[k] = acc[k] * sc + w * fsv;
            mh[k] = nm;
        }
    }

    float vout[KMAX];
    #pragma unroll
    for (int k = 0; k < KMAX; ++k) {
        float val = (lh[k] > 0.f) ? acc[k] / lh[k] : 0.f;
        if (HAS_RES) {
            int idx = k * 64 + lane;
            val += resid[(size_t)t * RS + idx];
        }
        if (DO_ELU) val = val > 0.f ? val : expm1f(val);
        vout[k] = val;
    }

    if (MEAN_OUT) {
        float ssum = 0.f;
        #pragma unroll
        for (int k = 0; k < KMAX; ++k) ssum += vout[k];
        ssum += __shfl_xor(ssum, 32, 64);
        if (lane < 32) out[(size_t)t * 32 + lane] = ssum * (1.f / 6.f);
    } else {
        #pragma unroll
        for (int k = 0; k < KMAX; ++k)
            out[(size_t)t * HD + k * 64 + lane] = vout[k];
    }
}

extern "C" void kernel_launch(void* const* d_in, const int* in_sizes, int n_in,
                              void* d_out, int out_size, void* d_ws, size_t ws_size,
                              hipStream_t stream) {
    const float* x   = (const float*)d_in[0];
    const int*   src = (const int*)d_in[1];
    const int*   dst = (const int*)d_in[2];
    const float* W0s = (const float*)d_in[3];
    const float* b0s = (const float*)d_in[4];
    const float* W0d = (const float*)d_in[5];
    const float* b0d = (const float*)d_in[6];
    const float* a0  = (const float*)d_in[7];
    const float* W1s = (const float*)d_in[8];
    const float* b1s = (const float*)d_in[9];
    const float* W1d = (const float*)d_in[10];
    const float* b1d = (const float*)d_in[11];
    const float* a1  = (const float*)d_in[12];
    const float* W2s = (const float*)d_in[13];
    const float* b2s = (const float*)d_in[14];
    const float* W2d = (const float*)d_in[15];
    const float* b2d = (const float*)d_in[16];
    const float* a2  = (const float*)d_in[17];
    const float* Wr2 = (const float*)d_in[18];
    const float* br2 = (const float*)d_in[19];

    // ---- workspace layout ----
    float* fsd = (float*)d_ws;                       // N*576 fp32 (max layer width)
    float* O0  = fsd + (size_t)NN * 576;             // N*256
    float* O1  = O0 + (size_t)NN * 256;              // N*256
    ushort* Ah = (ushort*)(O1 + (size_t)NN * 256);   // N*256 bf16
    ushort* Al = Ah + (size_t)NN * 256;              // N*256
    ushort* Wt0h = Al + (size_t)NN * 256;            // 512*128
    ushort* Wt0l = Wt0h + 512 * 128;
    ushort* Wt1h = Wt0l + 512 * 128;                 // 512*256
    ushort* Wt1l = Wt1h + 512 * 256;
    ushort* Wt2h = Wt1l + 512 * 256;                 // 576*256
    ushort* Wt2l = Wt2h + 576 * 256;
    float* bias0 = (float*)(Wt2l + 576 * 256);       // 512
    float* bias1 = bias0 + 512;                      // 512
    float* bias2 = bias1 + 512;                      // 576
    unsigned int* row_ptr = (unsigned int*)(bias2 + 576);  // N+1
    unsigned int* cursor  = row_ptr + (NN + 1);
    unsigned int* deg     = cursor + NN;
    int* csr_src          = (int*)(deg + NN);        // E

    // ---- build CSR ----
    zero_u32<<<(NN + 255) / 256, 256, 0, stream>>>(deg, NN);
    hist_dst<<<(EE + 255) / 256, 256, 0, stream>>>(dst, deg, EE);
    scan_deg<<<1, 1024, 0, stream>>>(deg, row_ptr, cursor, NN);
    scatter_edges<<<(EE + 255) / 256, 256, 0, stream>>>(src, dst, cursor, csr_src, EE);

    // ---- prep all weights ----
    prep_w<<<(512 * 128 + 255) / 256, 256, 0, stream>>>(
        W0s, b0s, 256, W0d, b0d, 256, nullptr, nullptr, 0, 128, Wt0h, Wt0l, bias0);
    prep_w<<<(512 * 256 + 255) / 256, 256, 0, stream>>>(
        W1s, b1s, 256, W1d, b1d, 256, nullptr, nullptr, 0, 256, Wt1h, Wt1l, bias1);
    prep_w<<<(576 * 256 + 255) / 256, 256, 0, stream>>>(
        W2s, b2s, 192, W2d, b2d, 192, Wr2, br2, 192, 256, Wt2h, Wt2l, bias2);

    const int nagg = (NN + 3) / 4;
    const int gy = (NN + 127) / 128;  // 157

    // ---- layer 0: x[N,128] -> fsd[N,512] -> O0[N,256] ----
    split_f32<<<((NN * 128 / 4) + 255) / 256, 256, 0, stream>>>(x, Ah, Al, NN * 128 / 4);
    gemm_mfma_split<<<dim3(8, gy), 256, 0, stream>>>(Ah, Al, Wt0h, Wt0l, bias0, fsd,
                                                     NN, 128, 512);
    gat_fused_aggregate<4, 64, false, true, false><<<nagg, 256, 0, stream>>>(
        fsd, 512, a0, row_ptr, csr_src, nullptr, 0, O0);

    // ---- layer 1: O0 -> fsd[N,512] -> O1[N,256] (identity residual) ----
    split_f32<<<((NN * 256 / 4) + 255) / 256, 256, 0, stream>>>(O0, Ah, Al, NN * 256 / 4);
    gemm_mfma_split<<<dim3(8, gy), 256, 0, stream>>>(Ah, Al, Wt1h, Wt1l, bias1, fsd,
                                                     NN, 256, 512);
    gat_fused_aggregate<4, 64, true, true, false><<<nagg, 256, 0, stream>>>(
        fsd, 512, a1, row_ptr, csr_src, O0, 256, O1);

    // ---- layer 2: O1 -> fsd[N,576] (fs|fd|res) -> d_out[N,32] ----
    split_f32<<<((NN * 256 / 4) + 255) / 256, 256, 0, stream>>>(O1, Ah, Al, NN * 256 / 4);
    gemm_mfma_split<<<dim3(9, gy), 256, 0, stream>>>(Ah, Al, Wt2h, Wt2l, bias2, fsd,
                                                     NN, 256, 576);
    gat_fused_aggregate<3, 32, true, false, true><<<nagg, 256, 0, stream>>>(
        fsd, 576, a2, row_ptr, csr_src, fsd + 384, 576, (float*)d_out);
}

// Round 4
// 522.157 us; speedup vs baseline: 3.4133x; 1.0859x over previous
//
#include <hip/hip_runtime.h>
#include <hip/hip_bf16.h>
#include <float.h>
#include <math.h>

// Problem constants (from reference)
#define NN 20000
#define EE 320000
#define IN_DIM 128
#define SLOPE_ 0.2f

typedef __attribute__((ext_vector_type(8))) short bf16x8;
typedef __attribute__((ext_vector_type(4))) float f32x4;
typedef unsigned short ushort;

// ---------- bf16 helpers ----------
__device__ inline ushort f32_to_bf16_rn(float f) {
    unsigned u = __float_as_uint(f);
    unsigned rounding = 0x7FFFu + ((u >> 16) & 1u);
    return (ushort)((u + rounding) >> 16);
}
__device__ inline float bf16u_to_f32(ushort h) {
    return __uint_as_float(((unsigned)h) << 16);
}

// ---------- split fp32 -> (hi, lo) bf16 (used only for input x) ----------
__global__ void split_f32(const float* __restrict__ A, ushort* __restrict__ hi,
                          ushort* __restrict__ lo, int n4) {
    int i = blockIdx.x * blockDim.x + threadIdx.x;
    if (i >= n4) return;
    float4 v = ((const float4*)A)[i];
    ushort h0 = f32_to_bf16_rn(v.x), h1 = f32_to_bf16_rn(v.y);
    ushort h2 = f32_to_bf16_rn(v.z), h3 = f32_to_bf16_rn(v.w);
    ushort l0 = f32_to_bf16_rn(v.x - bf16u_to_f32(h0));
    ushort l1 = f32_to_bf16_rn(v.y - bf16u_to_f32(h1));
    ushort l2 = f32_to_bf16_rn(v.z - bf16u_to_f32(h2));
    ushort l3 = f32_to_bf16_rn(v.w - bf16u_to_f32(h3));
    ((ushort4*)hi)[i] = make_ushort4(h0, h1, h2, h3);
    ((ushort4*)lo)[i] = make_ushort4(l0, l1, l2, l3);
}

// ---------- weight prep: concat + transpose + split, plus bias concat ----------
__global__ void prep_w(const float* __restrict__ Wa, const float* __restrict__ ba, int na,
                       const float* __restrict__ Wb, const float* __restrict__ bb, int nb,
                       const float* __restrict__ Wc, const float* __restrict__ bc, int nc,
                       int K, ushort* __restrict__ Wt_hi, ushort* __restrict__ Wt_lo,
                       float* __restrict__ bias_cat) {
    int idx = blockIdx.x * blockDim.x + threadIdx.x;
    int S = na + nb + nc;
    if (idx >= S * K) return;
    int n = idx / K;
    int k = idx - n * K;
    const float* W; const float* b; int nl; int ncols;
    if (n < na) { W = Wa; b = ba; nl = n; ncols = na; }
    else if (n < na + nb) { W = Wb; b = bb; nl = n - na; ncols = nb; }
    else { W = Wc; b = bc; nl = n - na - nb; ncols = nc; }
    float v = W[(size_t)k * ncols + nl];
    ushort h = f32_to_bf16_rn(v);
    ushort l = f32_to_bf16_rn(v - bf16u_to_f32(h));
    Wt_hi[(size_t)n * K + k] = h;
    Wt_lo[(size_t)n * K + k] = l;
    if (k == 0) bias_cat[n] = b[nl];
}

// ---------- split-bf16 MFMA GEMM: C[M][S] = A[M][K] @ Wt^T + bias ----------
#define BSTRIDE 40
__global__ __launch_bounds__(256) void gemm_mfma_split(
        const ushort* __restrict__ Ahi, const ushort* __restrict__ Alo,
        const ushort* __restrict__ Wth, const ushort* __restrict__ Wtl,
        const float* __restrict__ bias, float* __restrict__ C,
        int M, int K, int S) {
    __shared__ ushort Bs_hi[64 * BSTRIDE];
    __shared__ ushort Bs_lo[64 * BSTRIDE];
    const int bm = blockIdx.y * 128;
    const int bn = blockIdx.x * 64;
    const int tid = threadIdx.x;
    const int wave = tid >> 6;
    const int lane = tid & 63;
    const int m16 = lane & 15;
    const int quad = lane >> 4;

    f32x4 acc[2][4];
    #pragma unroll
    for (int i = 0; i < 2; ++i)
        #pragma unroll
        for (int j = 0; j < 4; ++j) acc[i][j] = (f32x4){0.f, 0.f, 0.f, 0.f};

    const int srow = tid >> 2;
    const int schk = tid & 3;

    for (int k0 = 0; k0 < K; k0 += 32) {
        {
            size_t goff = (size_t)(bn + srow) * K + k0 + schk * 8;
            bf16x8 vh = *(const bf16x8*)(Wth + goff);
            bf16x8 vl = *(const bf16x8*)(Wtl + goff);
            *(bf16x8*)&Bs_hi[srow * BSTRIDE + schk * 8] = vh;
            *(bf16x8*)&Bs_lo[srow * BSTRIDE + schk * 8] = vl;
        }
        bf16x8 ah[2], al[2];
        #pragma unroll
        for (int mt = 0; mt < 2; ++mt) {
            int row = bm + wave * 32 + mt * 16 + m16;
            row = row < M ? row : M - 1;
            size_t goff = (size_t)row * K + k0 + quad * 8;
            ah[mt] = *(const bf16x8*)(Ahi + goff);
            al[mt] = *(const bf16x8*)(Alo + goff);
        }
        __syncthreads();
        #pragma unroll
        for (int nt = 0; nt < 4; ++nt) {
            int boff = (nt * 16 + m16) * BSTRIDE + quad * 8;
            bf16x8 bh = *(const bf16x8*)&Bs_hi[boff];
            bf16x8 bl = *(const bf16x8*)&Bs_lo[boff];
            #pragma unroll
            for (int mt = 0; mt < 2; ++mt) {
                acc[mt][nt] = __builtin_amdgcn_mfma_f32_16x16x32_bf16(ah[mt], bh, acc[mt][nt], 0, 0, 0);
                acc[mt][nt] = __builtin_amdgcn_mfma_f32_16x16x32_bf16(ah[mt], bl, acc[mt][nt], 0, 0, 0);
                acc[mt][nt] = __builtin_amdgcn_mfma_f32_16x16x32_bf16(al[mt], bh, acc[mt][nt], 0, 0, 0);
            }
        }
        __syncthreads();
    }

    #pragma unroll
    for (int nt = 0; nt < 4; ++nt) {
        int col = bn + nt * 16 + m16;
        float bv = bias[col];
        #pragma unroll
        for (int mt = 0; mt < 2; ++mt) {
            #pragma unroll
            for (int r = 0; r < 4; ++r) {
                int row = bm + wave * 32 + mt * 16 + quad * 4 + r;
                if (row < M) C[(size_t)row * S + col] = acc[mt][nt][r] + bv;
            }
        }
    }
}

// ---------- CSR build ----------
__global__ void zero_u32(unsigned int* __restrict__ p, int n) {
    int i = blockIdx.x * blockDim.x + threadIdx.x;
    if (i < n) p[i] = 0u;
}

__global__ void hist_dst(const int* __restrict__ dst, unsigned int* __restrict__ deg, int E) {
    int e = blockIdx.x * blockDim.x + threadIdx.x;
    if (e < E) atomicAdd(&deg[dst[e]], 1u);
}

__global__ void scan_deg(const unsigned int* __restrict__ deg,
                         unsigned int* __restrict__ row_ptr,
                         unsigned int* __restrict__ cursor, int n) {
    __shared__ unsigned int sums[1024];
    const int t = threadIdx.x;
    const int chunk = (n + 1023) / 1024;
    const int start = t * chunk;
    const int end = min(start + chunk, n);
    unsigned int s = 0;
    for (int i = start; i < end; ++i) s += deg[i];
    sums[t] = s;
    __syncthreads();
    for (int off = 1; off < 1024; off <<= 1) {
        unsigned int v = (t >= off) ? sums[t - off] : 0u;
        __syncthreads();
        sums[t] += v;
        __syncthreads();
    }
    unsigned int prefix = (t == 0) ? 0u : sums[t - 1];
    for (int i = start; i < end; ++i) {
        row_ptr[i] = prefix;
        cursor[i] = prefix;
        prefix += deg[i];
    }
    if (t == 1023) row_ptr[n] = sums[1023];
}

__global__ void scatter_edges(const int* __restrict__ src, const int* __restrict__ dst,
                              unsigned int* __restrict__ cursor,
                              int* __restrict__ csr_src, int E) {
    int e = blockIdx.x * blockDim.x + threadIdx.x;
    if (e < E) {
        unsigned int pos = atomicAdd(&cursor[dst[e]], 1u);
        csr_src[pos] = src[e];
    }
}

// ---------- fused GATv2 aggregate: one wave per 64-dim slice of a node ----------
// Block = one node, SLICES waves. HD = SLICES*64, butterfly width D (head dim).
// OUT_MODE: 0 = write fp32 out + bf16 hi/lo; 1 = write bf16 hi/lo only;
//           2 = head-mean over 6 heads of 32 -> out[N,32].
template <int SLICES, int D, bool HAS_RES, bool DO_ELU, int OUT_MODE>
__global__ __launch_bounds__(SLICES * 64) void gat_slice_aggregate(
        const float* __restrict__ feat, int FS,
        const float* __restrict__ attn,
        const unsigned int* __restrict__ row_ptr,
        const int* __restrict__ csr_src,
        const float* __restrict__ resid, int RS,
        float* __restrict__ outF, ushort* __restrict__ outH, ushort* __restrict__ outL) {
    __shared__ float red[SLICES * 64];
    const int t = blockIdx.x;
    const int lane = threadIdx.x & 63;
    const int slice = threadIdx.x >> 6;
    const int HD = SLICES * 64;
    const int off = slice * 64 + lane;

    const float fdv = feat[(size_t)t * FS + HD + off];
    const float attnv = attn[off];
    float acc = 0.f, lh = 0.f, mh = -INFINITY;

    const unsigned int j0 = row_ptr[t], j1 = row_ptr[t + 1];
    // depth-2 software pipeline on the gather
    float f0 = 0.f, f1 = 0.f;
    if (j0 < j1) f0 = feat[(size_t)csr_src[j0] * FS + off];
    if (j0 + 1 < j1) f1 = feat[(size_t)csr_src[j0 + 1] * FS + off];
    for (unsigned int j = j0; j < j1; ++j) {
        const float fsv = f0;
        f0 = f1;
        if (j + 2 < j1) f1 = feat[(size_t)csr_src[j + 2] * FS + off];
        float v = fsv + fdv;
        v = v > 0.f ? v : SLOPE_ * v;
        float p = v * attnv;
        #pragma unroll
        for (int o = 1; o < D; o <<= 1)
            p += __shfl_xor(p, o, 64);
        float nm = fmaxf(mh, p);
        float sc = __expf(mh - nm);
        float w = __expf(p - nm);
        lh = lh * sc + w;
        acc = acc * sc + w * fsv;
        mh = nm;
    }

    float val = (lh > 0.f) ? acc / lh : 0.f;
    if (HAS_RES) val += resid[(size_t)t * RS + off];
    if (DO_ELU) val = val > 0.f ? val : expm1f(val);

    if (OUT_MODE == 2) {
        red[off] = val;
        __syncthreads();
        if (threadIdx.x < 32) {
            float ssum = 0.f;
            #pragma unroll
            for (int h = 0; h < 6; ++h) ssum += red[h * 32 + threadIdx.x];
            outF[(size_t)t * 32 + threadIdx.x] = ssum * (1.f / 6.f);
        }
    } else {
        ushort h = f32_to_bf16_rn(val);
        ushort l = f32_to_bf16_rn(val - bf16u_to_f32(h));
        outH[(size_t)t * HD + off] = h;
        outL[(size_t)t * HD + off] = l;
        if (OUT_MODE == 0) outF[(size_t)t * HD + off] = val;
    }
}

extern "C" void kernel_launch(void* const* d_in, const int* in_sizes, int n_in,
                              void* d_out, int out_size, void* d_ws, size_t ws_size,
                              hipStream_t stream) {
    const float* x   = (const float*)d_in[0];
    const int*   src = (const int*)d_in[1];
    const int*   dst = (const int*)d_in[2];
    const float* W0s = (const float*)d_in[3];
    const float* b0s = (const float*)d_in[4];
    const float* W0d = (const float*)d_in[5];
    const float* b0d = (const float*)d_in[6];
    const float* a0  = (const float*)d_in[7];
    const float* W1s = (const float*)d_in[8];
    const float* b1s = (const float*)d_in[9];
    const float* W1d = (const float*)d_in[10];
    const float* b1d = (const float*)d_in[11];
    const float* a1  = (const float*)d_in[12];
    const float* W2s = (const float*)d_in[13];
    const float* b2s = (const float*)d_in[14];
    const float* W2d = (const float*)d_in[15];
    const float* b2d = (const float*)d_in[16];
    const float* a2  = (const float*)d_in[17];
    const float* Wr2 = (const float*)d_in[18];
    const float* br2 = (const float*)d_in[19];

    // ---- workspace layout ----
    float* fsd = (float*)d_ws;                       // N*576 fp32 (max layer width)
    float* O0  = fsd + (size_t)NN * 576;             // N*256 (L0 out fp32 = L1 residual)
    ushort* Ah = (ushort*)(O0 + (size_t)NN * 256);   // N*256 bf16
    ushort* Al = Ah + (size_t)NN * 256;              // N*256
    ushort* Wt0h = Al + (size_t)NN * 256;            // 512*128
    ushort* Wt0l = Wt0h + 512 * 128;
    ushort* Wt1h = Wt0l + 512 * 128;                 // 512*256
    ushort* Wt1l = Wt1h + 512 * 256;
    ushort* Wt2h = Wt1l + 512 * 256;                 // 576*256
    ushort* Wt2l = Wt2h + 576 * 256;
    float* bias0 = (float*)(Wt2l + 576 * 256);       // 512
    float* bias1 = bias0 + 512;                      // 512
    float* bias2 = bias1 + 512;                      // 576
    unsigned int* row_ptr = (unsigned int*)(bias2 + 576);  // N+1
    unsigned int* cursor  = row_ptr + (NN + 1);
    unsigned int* deg     = cursor + NN;
    int* csr_src          = (int*)(deg + NN);        // E

    // ---- build CSR ----
    zero_u32<<<(NN + 255) / 256, 256, 0, stream>>>(deg, NN);
    hist_dst<<<(EE + 255) / 256, 256, 0, stream>>>(dst, deg, EE);
    scan_deg<<<1, 1024, 0, stream>>>(deg, row_ptr, cursor, NN);
    scatter_edges<<<(EE + 255) / 256, 256, 0, stream>>>(src, dst, cursor, csr_src, EE);

    // ---- prep all weights ----
    prep_w<<<(512 * 128 + 255) / 256, 256, 0, stream>>>(
        W0s, b0s, 256, W0d, b0d, 256, nullptr, nullptr, 0, 128, Wt0h, Wt0l, bias0);
    prep_w<<<(512 * 256 + 255) / 256, 256, 0, stream>>>(
        W1s, b1s, 256, W1d, b1d, 256, nullptr, nullptr, 0, 256, Wt1h, Wt1l, bias1);
    prep_w<<<(576 * 256 + 255) / 256, 256, 0, stream>>>(
        W2s, b2s, 192, W2d, b2d, 192, Wr2, br2, 192, 256, Wt2h, Wt2l, bias2);

    const int gy = (NN + 127) / 128;  // 157

    // ---- layer 0: x[N,128] -> fsd[N,512] -> O0 fp32 + Ah/Al bf16 ----
    split_f32<<<((NN * 128 / 4) + 255) / 256, 256, 0, stream>>>(x, Ah, Al, NN * 128 / 4);
    gemm_mfma_split<<<dim3(8, gy), 256, 0, stream>>>(Ah, Al, Wt0h, Wt0l, bias0, fsd,
                                                     NN, 128, 512);
    gat_slice_aggregate<4, 64, false, true, 0><<<NN, 256, 0, stream>>>(
        fsd, 512, a0, row_ptr, csr_src, nullptr, 0, O0, Ah, Al);

    // ---- layer 1: Ah/Al -> fsd[N,512] -> Ah/Al (identity residual O0) ----
    gemm_mfma_split<<<dim3(8, gy), 256, 0, stream>>>(Ah, Al, Wt1h, Wt1l, bias1, fsd,
                                                     NN, 256, 512);
    gat_slice_aggregate<4, 64, true, true, 1><<<NN, 256, 0, stream>>>(
        fsd, 512, a1, row_ptr, csr_src, O0, 256, nullptr, Ah, Al);

    // ---- layer 2: Ah/Al -> fsd[N,576] (fs|fd|res) -> d_out[N,32] ----
    gemm_mfma_split<<<dim3(9, gy), 256, 0, stream>>>(Ah, Al, Wt2h, Wt2l, bias2, fsd,
                                                     NN, 256, 576);
    gat_slice_aggregate<3, 32, true, false, 2><<<NN, 192, 0, stream>>>(
        fsd, 576, a2, row_ptr, csr_src, fsd + 384, 576, (float*)d_out, nullptr, nullptr);
}

// Round 5
// 443.125 us; speedup vs baseline: 4.0221x; 1.1784x over previous
//
#include <hip/hip_runtime.h>
#include <hip/hip_bf16.h>
#include <float.h>
#include <math.h>

// Problem constants (from reference)
#define NN 20000
#define EE 320000
#define IN_DIM 128
#define SLOPE_ 0.2f

typedef __attribute__((ext_vector_type(8))) short bf16x8;
typedef __attribute__((ext_vector_type(4))) float f32x4;
typedef unsigned short ushort;

// ---------- bf16 helpers ----------
__device__ inline ushort f32_to_bf16_rn(float f) {
    unsigned u = __float_as_uint(f);
    unsigned rounding = 0x7FFFu + ((u >> 16) & 1u);
    return (ushort)((u + rounding) >> 16);
}
__device__ inline float bf16u_to_f32(ushort h) {
    return __uint_as_float(((unsigned)h) << 16);
}

// ---------- split fp32 -> (hi, lo) bf16 (used only for input x) ----------
__global__ void split_f32(const float* __restrict__ A, ushort* __restrict__ hi,
                          ushort* __restrict__ lo, int n4) {
    int i = blockIdx.x * blockDim.x + threadIdx.x;
    if (i >= n4) return;
    float4 v = ((const float4*)A)[i];
    ushort h0 = f32_to_bf16_rn(v.x), h1 = f32_to_bf16_rn(v.y);
    ushort h2 = f32_to_bf16_rn(v.z), h3 = f32_to_bf16_rn(v.w);
    ushort l0 = f32_to_bf16_rn(v.x - bf16u_to_f32(h0));
    ushort l1 = f32_to_bf16_rn(v.y - bf16u_to_f32(h1));
    ushort l2 = f32_to_bf16_rn(v.z - bf16u_to_f32(h2));
    ushort l3 = f32_to_bf16_rn(v.w - bf16u_to_f32(h3));
    ((ushort4*)hi)[i] = make_ushort4(h0, h1, h2, h3);
    ((ushort4*)lo)[i] = make_ushort4(l0, l1, l2, l3);
}

// ---------- weight prep: concat + transpose + split, plus bias concat ----------
__global__ void prep_w(const float* __restrict__ Wa, const float* __restrict__ ba, int na,
                       const float* __restrict__ Wb, const float* __restrict__ bb, int nb,
                       const float* __restrict__ Wc, const float* __restrict__ bc, int nc,
                       int K, ushort* __restrict__ Wt_hi, ushort* __restrict__ Wt_lo,
                       float* __restrict__ bias_cat) {
    int idx = blockIdx.x * blockDim.x + threadIdx.x;
    int S = na + nb + nc;
    if (idx >= S * K) return;
    int n = idx / K;
    int k = idx - n * K;
    const float* W; const float* b; int nl; int ncols;
    if (n < na) { W = Wa; b = ba; nl = n; ncols = na; }
    else if (n < na + nb) { W = Wb; b = bb; nl = n - na; ncols = nb; }
    else { W = Wc; b = bc; nl = n - na - nb; ncols = nc; }
    float v = W[(size_t)k * ncols + nl];
    ushort h = f32_to_bf16_rn(v);
    ushort l = f32_to_bf16_rn(v - bf16u_to_f32(h));
    Wt_hi[(size_t)n * K + k] = h;
    Wt_lo[(size_t)n * K + k] = l;
    if (k == 0) bias_cat[n] = b[nl];
}

// ---------- split-bf16 MFMA GEMM: C[M][S] = A[M][K] @ Wt^T + bias ----------
#define BSTRIDE 40
__global__ __launch_bounds__(256) void gemm_mfma_split(
        const ushort* __restrict__ Ahi, const ushort* __restrict__ Alo,
        const ushort* __restrict__ Wth, const ushort* __restrict__ Wtl,
        const float* __restrict__ bias, float* __restrict__ C,
        int M, int K, int S) {
    __shared__ ushort Bs_hi[64 * BSTRIDE];
    __shared__ ushort Bs_lo[64 * BSTRIDE];
    const int bm = blockIdx.y * 128;
    const int bn = blockIdx.x * 64;
    const int tid = threadIdx.x;
    const int wave = tid >> 6;
    const int lane = tid & 63;
    const int m16 = lane & 15;
    const int quad = lane >> 4;

    f32x4 acc[2][4];
    #pragma unroll
    for (int i = 0; i < 2; ++i)
        #pragma unroll
        for (int j = 0; j < 4; ++j) acc[i][j] = (f32x4){0.f, 0.f, 0.f, 0.f};

    const int srow = tid >> 2;
    const int schk = tid & 3;

    for (int k0 = 0; k0 < K; k0 += 32) {
        {
            size_t goff = (size_t)(bn + srow) * K + k0 + schk * 8;
            bf16x8 vh = *(const bf16x8*)(Wth + goff);
            bf16x8 vl = *(const bf16x8*)(Wtl + goff);
            *(bf16x8*)&Bs_hi[srow * BSTRIDE + schk * 8] = vh;
            *(bf16x8*)&Bs_lo[srow * BSTRIDE + schk * 8] = vl;
        }
        bf16x8 ah[2], al[2];
        #pragma unroll
        for (int mt = 0; mt < 2; ++mt) {
            int row = bm + wave * 32 + mt * 16 + m16;
            row = row < M ? row : M - 1;
            size_t goff = (size_t)row * K + k0 + quad * 8;
            ah[mt] = *(const bf16x8*)(Ahi + goff);
            al[mt] = *(const bf16x8*)(Alo + goff);
        }
        __syncthreads();
        #pragma unroll
        for (int nt = 0; nt < 4; ++nt) {
            int boff = (nt * 16 + m16) * BSTRIDE + quad * 8;
            bf16x8 bh = *(const bf16x8*)&Bs_hi[boff];
            bf16x8 bl = *(const bf16x8*)&Bs_lo[boff];
            #pragma unroll
            for (int mt = 0; mt < 2; ++mt) {
                acc[mt][nt] = __builtin_amdgcn_mfma_f32_16x16x32_bf16(ah[mt], bh, acc[mt][nt], 0, 0, 0);
                acc[mt][nt] = __builtin_amdgcn_mfma_f32_16x16x32_bf16(ah[mt], bl, acc[mt][nt], 0, 0, 0);
                acc[mt][nt] = __builtin_amdgcn_mfma_f32_16x16x32_bf16(al[mt], bh, acc[mt][nt], 0, 0, 0);
            }
        }
        __syncthreads();
    }

    #pragma unroll
    for (int nt = 0; nt < 4; ++nt) {
        int col = bn + nt * 16 + m16;
        float bv = bias[col];
        #pragma unroll
        for (int mt = 0; mt < 2; ++mt) {
            #pragma unroll
            for (int r = 0; r < 4; ++r) {
                int row = bm + wave * 32 + mt * 16 + quad * 4 + r;
                if (row < M) C[(size_t)row * S + col] = acc[mt][nt][r] + bv;
            }
        }
    }
}

// ---------- CSR build ----------
__global__ void zero_u32(unsigned int* __restrict__ p, int n) {
    int i = blockIdx.x * blockDim.x + threadIdx.x;
    if (i < n) p[i] = 0u;
}

__global__ void hist_dst(const int* __restrict__ dst, unsigned int* __restrict__ deg, int E) {
    int e = blockIdx.x * blockDim.x + threadIdx.x;
    if (e < E) atomicAdd(&deg[dst[e]], 1u);
}

__global__ void scan_deg(const unsigned int* __restrict__ deg,
                         unsigned int* __restrict__ row_ptr,
                         unsigned int* __restrict__ cursor, int n) {
    __shared__ unsigned int sums[1024];
    const int t = threadIdx.x;
    const int chunk = (n + 1023) / 1024;
    const int start = t * chunk;
    const int end = min(start + chunk, n);
    unsigned int s = 0;
    for (int i = start; i < end; ++i) s += deg[i];
    sums[t] = s;
    __syncthreads();
    for (int off = 1; off < 1024; off <<= 1) {
        unsigned int v = (t >= off) ? sums[t - off] : 0u;
        __syncthreads();
        sums[t] += v;
        __syncthreads();
    }
    unsigned int prefix = (t == 0) ? 0u : sums[t - 1];
    for (int i = start; i < end; ++i) {
        row_ptr[i] = prefix;
        cursor[i] = prefix;
        prefix += deg[i];
    }
    if (t == 1023) row_ptr[n] = sums[1023];
}

__global__ void scatter_edges(const int* __restrict__ src, const int* __restrict__ dst,
                              unsigned int* __restrict__ cursor,
                              int* __restrict__ csr_src, int E) {
    int e = blockIdx.x * blockDim.x + threadIdx.x;
    if (e < E) {
        unsigned int pos = atomicAdd(&cursor[dst[e]], 1u);
        csr_src[pos] = src[e];
    }
}

// ---------- fused GATv2 aggregate: one wave per node, float4 lanes ----------
// Lane i owns dims 4i..4i+3 (one head: 4 | D). Butterfly over D/4 lanes.
// OUT_MODE: 0 = fp32 out + bf16 hi/lo; 1 = bf16 hi/lo only; 2 = head-mean -> out[N,32].
template <int HD, int D, bool HAS_RES, bool DO_ELU, int OUT_MODE>
__global__ __launch_bounds__(256) void gat_node_aggregate(
        const float* __restrict__ feat, int FS,
        const float* __restrict__ attn,
        const unsigned int* __restrict__ row_ptr,
        const int* __restrict__ csr_src,
        const float* __restrict__ resid, int RS,
        float* __restrict__ outF, ushort* __restrict__ outH, ushort* __restrict__ outL) {
    constexpr int LANES = HD / 4;   // active lanes per node (64 or 48)
    constexpr int GSZ = D / 4;      // lanes per head group (16 or 8)
    __shared__ float red[4][(OUT_MODE == 2) ? HD : 1];

    const int wave = threadIdx.x >> 6;
    const int lane = threadIdx.x & 63;
    const int t = blockIdx.x * 4 + wave;
    const bool active = (lane < LANES);
    const int off = active ? 4 * lane : 0;

    float4 fdv = make_float4(0.f, 0.f, 0.f, 0.f);
    float4 a6 = fdv, a4 = fdv;
    if (active) {
        fdv = *(const float4*)&feat[(size_t)t * FS + HD + off];
        float4 a = *(const float4*)&attn[off];
        a6 = make_float4(0.6f * a.x, 0.6f * a.y, 0.6f * a.z, 0.6f * a.w);
        a4 = make_float4(0.4f * a.x, 0.4f * a.y, 0.4f * a.z, 0.4f * a.w);
    }

    float4 acc = make_float4(0.f, 0.f, 0.f, 0.f);
    float lh = 0.f, mh = -INFINITY;

    const unsigned int j0 = row_ptr[t], j1 = row_ptr[t + 1];
    float4 f0 = acc, f1 = acc;
    if (active && j0 < j1) f0 = *(const float4*)&feat[(size_t)csr_src[j0] * FS + off];
    if (active && j0 + 1 < j1) f1 = *(const float4*)&feat[(size_t)csr_src[j0 + 1] * FS + off];

    for (unsigned int j = j0; j < j1; ++j) {
        const float4 fsv = f0;
        f0 = f1;
        if (active && j + 2 < j1) f1 = *(const float4*)&feat[(size_t)csr_src[j + 2] * FS + off];
        // lrelu(x)*a = x*(0.6a) + |x|*(0.4a)
        float x0 = fsv.x + fdv.x, x1 = fsv.y + fdv.y;
        float x2 = fsv.z + fdv.z, x3 = fsv.w + fdv.w;
        float p = x0 * a6.x + fabsf(x0) * a4.x;
        p += x1 * a6.y + fabsf(x1) * a4.y;
        p += x2 * a6.z + fabsf(x2) * a4.z;
        p += x3 * a6.w + fabsf(x3) * a4.w;
        #pragma unroll
        for (int o = 1; o < GSZ; o <<= 1)
            p += __shfl_xor(p, o, 64);
        float nm = fmaxf(mh, p);
        float sc = __expf(mh - nm);
        float w = __expf(p - nm);
        lh = lh * sc + w;
        acc.x = acc.x * sc + w * fsv.x;
        acc.y = acc.y * sc + w * fsv.y;
        acc.z = acc.z * sc + w * fsv.z;
        acc.w = acc.w * sc + w * fsv.w;
        mh = nm;
    }

    float inv = (lh > 0.f) ? 1.f / lh : 0.f;
    float4 vout = make_float4(acc.x * inv, acc.y * inv, acc.z * inv, acc.w * inv);
    if (HAS_RES && active) {
        float4 r = *(const float4*)&resid[(size_t)t * RS + off];
        vout.x += r.x; vout.y += r.y; vout.z += r.z; vout.w += r.w;
    }
    if (DO_ELU) {
        vout.x = vout.x > 0.f ? vout.x : expm1f(vout.x);
        vout.y = vout.y > 0.f ? vout.y : expm1f(vout.y);
        vout.z = vout.z > 0.f ? vout.z : expm1f(vout.z);
        vout.w = vout.w > 0.f ? vout.w : expm1f(vout.w);
    }

    if (OUT_MODE == 2) {
        if (active) *(float4*)&red[wave][off] = vout;
        __syncthreads();
        if (lane < 32) {
            float ssum = 0.f;
            #pragma unroll
            for (int h = 0; h < 6; ++h) ssum += red[wave][h * 32 + lane];
            outF[(size_t)t * 32 + lane] = ssum * (1.f / 6.f);
        }
    } else if (active) {
        ushort4 hv = make_ushort4(f32_to_bf16_rn(vout.x), f32_to_bf16_rn(vout.y),
                                  f32_to_bf16_rn(vout.z), f32_to_bf16_rn(vout.w));
        ushort4 lv = make_ushort4(f32_to_bf16_rn(vout.x - bf16u_to_f32(hv.x)),
                                  f32_to_bf16_rn(vout.y - bf16u_to_f32(hv.y)),
                                  f32_to_bf16_rn(vout.z - bf16u_to_f32(hv.z)),
                                  f32_to_bf16_rn(vout.w - bf16u_to_f32(hv.w)));
        *(ushort4*)&outH[(size_t)t * HD + off] = hv;
        *(ushort4*)&outL[(size_t)t * HD + off] = lv;
        if (OUT_MODE == 0) *(float4*)&outF[(size_t)t * HD + off] = vout;
    }
}

extern "C" void kernel_launch(void* const* d_in, const int* in_sizes, int n_in,
                              void* d_out, int out_size, void* d_ws, size_t ws_size,
                              hipStream_t stream) {
    const float* x   = (const float*)d_in[0];
    const int*   src = (const int*)d_in[1];
    const int*   dst = (const int*)d_in[2];
    const float* W0s = (const float*)d_in[3];
    const float* b0s = (const float*)d_in[4];
    const float* W0d = (const float*)d_in[5];
    const float* b0d = (const float*)d_in[6];
    const float* a0  = (const float*)d_in[7];
    const float* W1s = (const float*)d_in[8];
    const float* b1s = (const float*)d_in[9];
    const float* W1d = (const float*)d_in[10];
    const float* b1d = (const float*)d_in[11];
    const float* a1  = (const float*)d_in[12];
    const float* W2s = (const float*)d_in[13];
    const float* b2s = (const float*)d_in[14];
    const float* W2d = (const float*)d_in[15];
    const float* b2d = (const float*)d_in[16];
    const float* a2  = (const float*)d_in[17];
    const float* Wr2 = (const float*)d_in[18];
    const float* br2 = (const float*)d_in[19];

    // ---- workspace layout ----
    float* fsd = (float*)d_ws;                       // N*576 fp32 (max layer width)
    float* O0  = fsd + (size_t)NN * 576;             // N*256 (L0 out fp32 = L1 residual)
    ushort* Ah = (ushort*)(O0 + (size_t)NN * 256);   // N*256 bf16
    ushort* Al = Ah + (size_t)NN * 256;              // N*256
    ushort* Wt0h = Al + (size_t)NN * 256;            // 512*128
    ushort* Wt0l = Wt0h + 512 * 128;
    ushort* Wt1h = Wt0l + 512 * 128;                 // 512*256
    ushort* Wt1l = Wt1h + 512 * 256;
    ushort* Wt2h = Wt1l + 512 * 256;                 // 576*256
    ushort* Wt2l = Wt2h + 576 * 256;
    float* bias0 = (float*)(Wt2l + 576 * 256);       // 512
    float* bias1 = bias0 + 512;                      // 512
    float* bias2 = bias1 + 512;                      // 576
    unsigned int* row_ptr = (unsigned int*)(bias2 + 576);  // N+1
    unsigned int* cursor  = row_ptr + (NN + 1);
    unsigned int* deg     = cursor + NN;
    int* csr_src          = (int*)(deg + NN);        // E

    // ---- build CSR ----
    zero_u32<<<(NN + 255) / 256, 256, 0, stream>>>(deg, NN);
    hist_dst<<<(EE + 255) / 256, 256, 0, stream>>>(dst, deg, EE);
    scan_deg<<<1, 1024, 0, stream>>>(deg, row_ptr, cursor, NN);
    scatter_edges<<<(EE + 255) / 256, 256, 0, stream>>>(src, dst, cursor, csr_src, EE);

    // ---- prep all weights ----
    prep_w<<<(512 * 128 + 255) / 256, 256, 0, stream>>>(
        W0s, b0s, 256, W0d, b0d, 256, nullptr, nullptr, 0, 128, Wt0h, Wt0l, bias0);
    prep_w<<<(512 * 256 + 255) / 256, 256, 0, stream>>>(
        W1s, b1s, 256, W1d, b1d, 256, nullptr, nullptr, 0, 256, Wt1h, Wt1l, bias1);
    prep_w<<<(576 * 256 + 255) / 256, 256, 0, stream>>>(
        W2s, b2s, 192, W2d, b2d, 192, Wr2, br2, 192, 256, Wt2h, Wt2l, bias2);

    const int gy = (NN + 127) / 128;  // 157
    const int nagg = NN / 4;          // 5000 blocks, 4 nodes (waves) each

    // ---- layer 0: x[N,128] -> fsd[N,512] -> O0 fp32 + Ah/Al bf16 ----
    split_f32<<<((NN * 128 / 4) + 255) / 256, 256, 0, stream>>>(x, Ah, Al, NN * 128 / 4);
    gemm_mfma_split<<<dim3(8, gy), 256, 0, stream>>>(Ah, Al, Wt0h, Wt0l, bias0, fsd,
                                                     NN, 128, 512);
    gat_node_aggregate<256, 64, false, true, 0><<<nagg, 256, 0, stream>>>(
        fsd, 512, a0, row_ptr, csr_src, nullptr, 0, O0, Ah, Al);

    // ---- layer 1: Ah/Al -> fsd[N,512] -> Ah/Al (identity residual O0) ----
    gemm_mfma_split<<<dim3(8, gy), 256, 0, stream>>>(Ah, Al, Wt1h, Wt1l, bias1, fsd,
                                                     NN, 256, 512);
    gat_node_aggregate<256, 64, true, true, 1><<<nagg, 256, 0, stream>>>(
        fsd, 512, a1, row_ptr, csr_src, O0, 256, nullptr, Ah, Al);

    // ---- layer 2: Ah/Al -> fsd[N,576] (fs|fd|res) -> d_out[N,32] ----
    gemm_mfma_split<<<dim3(9, gy), 256, 0, stream>>>(Ah, Al, Wt2h, Wt2l, bias2, fsd,
                                                     NN, 256, 576);
    gat_node_aggregate<192, 32, true, false, 2><<<nagg, 256, 0, stream>>>(
        fsd, 576, a2, row_ptr, csr_src, fsd + 384, 576, (float*)d_out, nullptr, nullptr);
}